// Round 2
// baseline (329.995 us; speedup 1.0000x reference)
//
#include <hip/hip_runtime.h>

// Problem constants (match reference file)
#define N_NODES 500000
#define DIM     128       // hidden channels
#define BATCH   8192      // triplets
#define KNB     64        // neighbors per disease
#define LAMBDA  0.7f

// ---------------------------------------------------------------------------
// Kernel 1: tag[n] = -1 for all nodes
// ---------------------------------------------------------------------------
__global__ void k_init_tag(int* __restrict__ tag) {
    int i = blockIdx.x * blockDim.x + threadIdx.x;
    if (i < N_NODES) tag[i] = -1;
}

// ---------------------------------------------------------------------------
// Kernel 2: tag[head[b]] = max b  (last-write-wins winner per node)
// ---------------------------------------------------------------------------
__global__ void k_tag(const int* __restrict__ head, int* __restrict__ tag) {
    int b = blockIdx.x * blockDim.x + threadIdx.x;
    if (b < BATCH) atomicMax(&tag[head[b]], b);
}

// ---------------------------------------------------------------------------
// Kernel 3: dense update-row compute. One 128-thread block per triplet b.
// Only "winners" (masked && last writer of their head) do work; others exit
// after 3 scalar-ish loads. Reads ORIGINAL node_emb (reference semantics).
// upd[b][d] = c * sum_k w_k*emb[nb_k][d] + (1-c)*emb[h][d]
// ---------------------------------------------------------------------------
__global__ __launch_bounds__(128)
void k_update(const int*   __restrict__ head,
              const int*   __restrict__ rel_type,
              const int*   __restrict__ tag,
              const float* __restrict__ node_emb,
              const int*   __restrict__ local_idx_map,
              const int*   __restrict__ sim_neighbors,
              const float* __restrict__ sim_weights,
              const int*   __restrict__ degree_table,
              float*       __restrict__ upd)
{
    int b  = blockIdx.x;
    int rt = rel_type[b];
    if (rt < 2 || rt > 4) return;          // unmasked: no update row needed
    int h = head[b];
    if (tag[h] != b) return;               // not the last writer: row discarded

    __shared__ int   s_nb[KNB];
    __shared__ float s_wt[KNB];

    int tid = threadIdx.x;                 // 0..127 == dim index
    int loc = local_idx_map[h];
    if (tid < KNB)
        s_nb[tid] = sim_neighbors[(size_t)loc * KNB + tid];
    else
        s_wt[tid - KNB] = sim_weights[(size_t)loc * KNB + (tid - KNB)];
    __syncthreads();

    float deg = (float)degree_table[loc * 3 + (rt - 2)];
    float c   = LAMBDA * __expf(-LAMBDA * deg) + 0.2f;

    float oldv = node_emb[(size_t)h * DIM + tid];

    float acc = 0.0f;
    #pragma unroll 8
    for (int k = 0; k < KNB; ++k) {
        // s_nb[k]/s_wt[k]: LDS same-address broadcast (conflict-free)
        acc += s_wt[k] * node_emb[(size_t)s_nb[k] * DIM + tid];
    }

    upd[(size_t)b * DIM + tid] = c * acc + (1.0f - c) * oldv;
}

// ---------------------------------------------------------------------------
// Kernel 4: scatter winners' update rows into node_emb (in place).
// Distinct winners have distinct head nodes -> no write races.
// Unmasked winners would write back the old row -> skip (no-op).
// ---------------------------------------------------------------------------
__global__ __launch_bounds__(128)
void k_scatter(const int*   __restrict__ head,
               const int*   __restrict__ rel_type,
               const int*   __restrict__ tag,
               const float* __restrict__ upd,
               float*       __restrict__ node_emb)
{
    int b  = blockIdx.x;
    int rt = rel_type[b];
    if (rt < 2 || rt > 4) return;
    int h = head[b];
    if (tag[h] != b) return;

    int tid = threadIdx.x;
    node_emb[(size_t)h * DIM + tid] = upd[(size_t)b * DIM + tid];
}

// ---------------------------------------------------------------------------
// Kernel 5: branch-free DistMult score on the updated table.
// One wave per triplet, 2 dims/lane as float2.
// ---------------------------------------------------------------------------
__global__ __launch_bounds__(256)
void k_score(const int*   __restrict__ head,
             const int*   __restrict__ rel_type,
             const int*   __restrict__ tail,
             const float* __restrict__ node_emb,
             const float* __restrict__ rel_emb,
             float*       __restrict__ out)
{
    int lane = threadIdx.x & 63;
    int wid  = threadIdx.x >> 6;
    int b    = blockIdx.x * (blockDim.x >> 6) + wid;
    if (b >= BATCH) return;

    int h = head[b];
    int t = tail[b];
    int r = rel_type[b];

    const float2* hrow = (const float2*)(node_emb + (size_t)h * DIM);
    const float2* trow = (const float2*)(node_emb + (size_t)t * DIM);
    const float2* rrow = (const float2*)(rel_emb  + (size_t)r * DIM);

    float2 hv = hrow[lane];
    float2 tv = trow[lane];
    float2 rv = rrow[lane];

    float p = hv.x * rv.x * tv.x + hv.y * rv.y * tv.y;

    #pragma unroll
    for (int off = 32; off > 0; off >>= 1)
        p += __shfl_down(p, off, 64);

    if (lane == 0) out[b] = p;
}

// ---------------------------------------------------------------------------
// kernel_launch
// d_in order: head_index, rel_type, tail_index, node_emb, rel_emb,
//             local_idx_map, sim_neighbors, sim_weights, degree_table
// ---------------------------------------------------------------------------
extern "C" void kernel_launch(void* const* d_in, const int* in_sizes, int n_in,
                              void* d_out, int out_size, void* d_ws, size_t ws_size,
                              hipStream_t stream) {
    const int*   head     = (const int*)  d_in[0];
    const int*   rel_type = (const int*)  d_in[1];
    const int*   tail     = (const int*)  d_in[2];
    float*       node_emb = (float*)      d_in[3];   // mutated; harness restores
    const float* rel_emb  = (const float*)d_in[4];
    const int*   lmap     = (const int*)  d_in[5];
    const int*   sn       = (const int*)  d_in[6];
    const float* sw       = (const float*)d_in[7];
    const int*   dt       = (const int*)  d_in[8];
    float*       out      = (float*)      d_out;

    // workspace layout: tag[N] (2 MB) | upd[B][D] (4 MB)
    int*   tag = (int*)d_ws;
    float* upd = (float*)((char*)d_ws + ((size_t)N_NODES * 4 + 511) / 512 * 512);

    k_init_tag<<<(N_NODES + 255) / 256, 256, 0, stream>>>(tag);
    k_tag<<<(BATCH + 255) / 256, 256, 0, stream>>>(head, tag);
    k_update<<<BATCH, 128, 0, stream>>>(head, rel_type, tag, node_emb,
                                        lmap, sn, sw, dt, upd);
    k_scatter<<<BATCH, 128, 0, stream>>>(head, rel_type, tag, upd, node_emb);
    k_score<<<BATCH / 4, 256, 0, stream>>>(head, rel_type, tail,
                                           node_emb, rel_emb, out);
}

// Round 3
// 328.152 us; speedup vs baseline: 1.0056x; 1.0056x over previous
//
#include <hip/hip_runtime.h>

// Problem constants (match reference file)
#define N_NODES 500000
#define DIM     128       // hidden channels
#define BATCH   8192      // triplets
#define KNB     64        // neighbors per disease
#define LAMBDA  0.7f

// ---------------------------------------------------------------------------
// Kernel 1: tag[n] = -1 for all nodes (cheap: 2 MB; do not trust ws poison)
// ---------------------------------------------------------------------------
__global__ void k_init_tag(int* __restrict__ tag) {
    int i = blockIdx.x * blockDim.x + threadIdx.x;
    if (i < N_NODES) tag[i] = -1;
}

// ---------------------------------------------------------------------------
// Kernel 2: tag[head[b]] = max b  (last-write-wins winner per node)
// ---------------------------------------------------------------------------
__global__ void k_tag(const int* __restrict__ head, int* __restrict__ tag) {
    int b = blockIdx.x * blockDim.x + threadIdx.x;
    if (b < BATCH) atomicMax(&tag[head[b]], b);
}

// ---------------------------------------------------------------------------
// Kernel 3: dense update-row compute. One 128-thread block per triplet b.
// Only winners (masked && last writer of their head) do work. Reads the
// ORIGINAL node_emb (reference: disease_vec gathers pre-update table).
// upd[b][d] = c * sum_k w_k*emb[nb_k][d] + (1-c)*emb[h][d]
// ---------------------------------------------------------------------------
__global__ __launch_bounds__(128)
void k_update(const int*   __restrict__ head,
              const int*   __restrict__ rel_type,
              const int*   __restrict__ tag,
              const float* __restrict__ node_emb,
              const int*   __restrict__ local_idx_map,
              const int*   __restrict__ sim_neighbors,
              const float* __restrict__ sim_weights,
              const int*   __restrict__ degree_table,
              float*       __restrict__ upd)
{
    int b  = blockIdx.x;
    int rt = rel_type[b];
    if (rt < 2 || rt > 4) return;          // unmasked: row never read by score
    int h = head[b];
    if (tag[h] != b) return;               // not the winner: row never read

    __shared__ int   s_nb[KNB];
    __shared__ float s_wt[KNB];

    int tid = threadIdx.x;                 // 0..127 == dim index
    int loc = local_idx_map[h];
    if (tid < KNB)
        s_nb[tid] = sim_neighbors[(size_t)loc * KNB + tid];
    else
        s_wt[tid - KNB] = sim_weights[(size_t)loc * KNB + (tid - KNB)];
    __syncthreads();

    float deg = (float)degree_table[loc * 3 + (rt - 2)];
    float c   = LAMBDA * __expf(-LAMBDA * deg) + 0.2f;

    float oldv = node_emb[(size_t)h * DIM + tid];

    float acc = 0.0f;
    #pragma unroll 8
    for (int k = 0; k < KNB; ++k) {
        // s_nb[k]/s_wt[k]: LDS same-address broadcast (conflict-free)
        acc += s_wt[k] * node_emb[(size_t)s_nb[k] * DIM + tid];
    }

    upd[(size_t)b * DIM + tid] = c * acc + (1.0f - c) * oldv;
}

// ---------------------------------------------------------------------------
// Row resolver for the post-scatter table WITHOUT materializing it:
// node n's effective row is upd[tag[n]] iff its winner exists and is masked,
// else the original node_emb row. Wave-uniform select (n uniform per wave).
// ---------------------------------------------------------------------------
__device__ __forceinline__ const float2* row_ptr(
    int n,
    const int*   __restrict__ tag,
    const int*   __restrict__ rel_type,
    const float* __restrict__ node_emb,
    const float* __restrict__ upd)
{
    const float* base = node_emb + (size_t)n * DIM;
    int w = tag[n];
    if (w >= 0) {
        int rw = rel_type[w];
        if ((unsigned)(rw - 2) <= 2u)      // winner masked -> updated row
            base = upd + (size_t)w * DIM;
    }
    return (const float2*)base;
}

// ---------------------------------------------------------------------------
// Kernel 4: DistMult score. One wave per triplet, 2 dims/lane as float2.
// ---------------------------------------------------------------------------
__global__ __launch_bounds__(256)
void k_score(const int*   __restrict__ head,
             const int*   __restrict__ rel_type,
             const int*   __restrict__ tail,
             const float* __restrict__ node_emb,
             const float* __restrict__ rel_emb,
             const int*   __restrict__ tag,
             const float* __restrict__ upd,
             float*       __restrict__ out)
{
    int lane = threadIdx.x & 63;
    int wid  = threadIdx.x >> 6;
    int b    = blockIdx.x * (blockDim.x >> 6) + wid;
    if (b >= BATCH) return;

    int h = head[b];
    int t = tail[b];
    int r = rel_type[b];

    const float2* hrow = row_ptr(h, tag, rel_type, node_emb, upd);
    const float2* trow = row_ptr(t, tag, rel_type, node_emb, upd);
    const float2* rrow = (const float2*)(rel_emb + (size_t)r * DIM);

    float2 hv = hrow[lane];
    float2 tv = trow[lane];
    float2 rv = rrow[lane];

    float p = hv.x * rv.x * tv.x + hv.y * rv.y * tv.y;

    #pragma unroll
    for (int off = 32; off > 0; off >>= 1)
        p += __shfl_down(p, off, 64);

    if (lane == 0) out[b] = p;
}

// ---------------------------------------------------------------------------
// kernel_launch
// d_in order: head_index, rel_type, tail_index, node_emb, rel_emb,
//             local_idx_map, sim_neighbors, sim_weights, degree_table
// ---------------------------------------------------------------------------
extern "C" void kernel_launch(void* const* d_in, const int* in_sizes, int n_in,
                              void* d_out, int out_size, void* d_ws, size_t ws_size,
                              hipStream_t stream) {
    const int*   head     = (const int*)  d_in[0];
    const int*   rel_type = (const int*)  d_in[1];
    const int*   tail     = (const int*)  d_in[2];
    const float* node_emb = (const float*)d_in[3];   // never mutated
    const float* rel_emb  = (const float*)d_in[4];
    const int*   lmap     = (const int*)  d_in[5];
    const int*   sn       = (const int*)  d_in[6];
    const float* sw       = (const float*)d_in[7];
    const int*   dt       = (const int*)  d_in[8];
    float*       out      = (float*)      d_out;

    // workspace layout: tag[N] (2 MB) | pad | upd[B][D] (4 MB)
    int*   tag = (int*)d_ws;
    float* upd = (float*)((char*)d_ws + (size_t)4 * 1024 * 1024);

    k_init_tag<<<(N_NODES + 255) / 256, 256, 0, stream>>>(tag);
    k_tag<<<(BATCH + 255) / 256, 256, 0, stream>>>(head, tag);
    k_update<<<BATCH, 128, 0, stream>>>(head, rel_type, tag, node_emb,
                                        lmap, sn, sw, dt, upd);
    k_score<<<BATCH / 4, 256, 0, stream>>>(head, rel_type, tail,
                                           node_emb, rel_emb, tag, upd, out);
}